// Round 2
// baseline (570.597 us; speedup 1.0000x reference)
//
#include <hip/hip_runtime.h>

// Problem constants: B=16, G=8192, C=16, S=8, L=3, m=1, infer_step=4
constexpr int B = 16;
constexpr int G = 8192;
constexpr int C = 16;
constexpr int S = 8;
constexpr int L = 3;
constexpr int STEPS = 4;
constexpr int NSLOT = 32;   // atomic-max spreading slots

#define K_E   144.269504088896f   // 1/(gamma*ln2), gamma=0.01
#define GLN2  0.00693147180560f   // gamma*ln2

typedef float f4 __attribute__((ext_vector_type(4)));

__device__ __forceinline__ float fexp2(float x){ return __builtin_amdgcn_exp2f(x); }
__device__ __forceinline__ float flog2(float x){ return __builtin_amdgcn_logf(x); }

// all tracked values are >= 0, so uint-bit compare == float compare
__device__ __forceinline__ void atomicMaxF(float* p, float v){
    atomicMax(reinterpret_cast<unsigned int*>(p), __float_as_uint(v));
}

__device__ __forceinline__ float waveMax(float v){
    #pragma unroll
    for (int off = 32; off > 0; off >>= 1)
        v = fmaxf(v, __shfl_down(v, off));
    return v;
}

__device__ __forceinline__ float maxOf32(const float* __restrict__ p){
    float m = p[0];
    #pragma unroll
    for (int i = 1; i < NSLOT; i++) m = fmaxf(m, p[i]);
    return m;
}

// ws float layout:
//   [0..15]           wstar
//   [16 .. 16+416)    gm slots: per step s: [s*96 .. ) = gmLs[32], gmHu[32], gmT[32]
//                     [384..416) = identity "prev max" array (max = 1.0)
//   then T0 (G*B), T1 (G*B), Hu (G*B)

__global__ void init_kernel(const float* __restrict__ W, float* __restrict__ wstar,
                            float* __restrict__ gm){
    int t = threadIdx.x;
    // zero all 416 slot floats
    for (int i = t; i < 4*96 + NSLOT; i += 64) gm[i] = 0.f;
    if (t == 0){
        gm[4*96] = 1.0f;   // identity prev-max
        float mx = -1e30f;
        for (int c = 0; c < C; c++) mx = fmaxf(mx, W[c]);
        float e[C]; float s = 0.f;
        for (int c = 0; c < C; c++){ e[c] = fexp2((W[c]-mx)*1.44269504089f); s += e[c]; }
        for (int c = 0; c < C; c++) wstar[c] = e[c] / s;
    }
}

// x (B,G) -> T0 (G,B)
__global__ void transpose_kernel(const float* __restrict__ x, float* __restrict__ T0){
    int tid = blockIdx.x*256 + threadIdx.x;      // tid = b*G + g
    int b = tid >> 13;                           // G = 8192
    int g = tid & (G-1);
    T0[g*B + b] = x[tid];
}

// Kernel 1 per step: one block per g (8192 blocks), 256 threads = 16 c x 16 b.
// Thread (c,b): gather 24 state values (16-lane b-groups read full 64B rows,
// coalesced), body products, LSE over S=8 -> ls.  Block-reduce Hu over c.
__global__ __launch_bounds__(256) void clause_kernel(
        const float* __restrict__ Tin,     // (G,B) unnormalized state
        const int*   __restrict__ I,       // (C,G,S,L)
        const float* __restrict__ wstar,   // (C)
        const float* __restrict__ gmPrev,  // 32 slots: max -> prev T gmax
        float* __restrict__ gmLs,          // 32 slots atomic out
        float* __restrict__ gmHu,          // 32 slots atomic out
        float* __restrict__ Hu)            // (G,B) out
{
    const int tid = threadIdx.x;
    const int c = tid >> 4;
    const int b = tid & 15;
    const int g = blockIdx.x;

    const float scPrev = 1.0f / fmaxf(maxOf32(gmPrev), 1.0f);
    const float sc3 = scPrev * scPrev * scPrev;

    const int* Ip = I + ((size_t)c*G + g) * (S*L);
    int idx[S*L];
    #pragma unroll
    for (int i = 0; i < 6; i++){
        int4 v = ((const int4*)Ip)[i];
        idx[i*4+0] = v.x; idx[i*4+1] = v.y; idx[i*4+2] = v.z; idx[i*4+3] = v.w;
    }

    float gv[S*L];
    #pragma unroll
    for (int j = 0; j < S*L; j++) gv[j] = Tin[idx[j]*B + b];

    float body[S];
    #pragma unroll
    for (int s = 0; s < S; s++) body[s] = gv[s*3+0] * gv[s*3+1] * gv[s*3+2] * sc3;

    float m = body[0];
    #pragma unroll
    for (int s = 1; s < S; s++) m = fmaxf(m, body[s]);
    float sum = 0.f;
    #pragma unroll
    for (int s = 0; s < S; s++) sum += fexp2((body[s] - m) * K_E);
    const float ls = m + GLN2 * flog2(sum);

    __shared__ float wls[C*17];
    __shared__ float smax[4];
    wls[c*17 + b] = wstar[c] * ls;
    float wm = waveMax(ls);
    if ((tid & 63) == 0) smax[tid >> 6] = wm;
    __syncthreads();

    float hu = 0.f;
    if (tid < 16){
        #pragma unroll
        for (int cc = 0; cc < C; cc++) hu += wls[cc*17 + tid];
        Hu[(size_t)g*B + tid] = hu;
    }
    if (tid < 64){
        float wmh = waveMax(hu);   // lanes >=16 contribute 0
        if (tid == 0){
            atomicMaxF(&gmHu[g & (NSLOT-1)], wmh);
            float bm = fmaxf(fmaxf(smax[0], smax[1]), fmaxf(smax[2], smax[3]));
            atomicMaxF(&gmLs[g & (NSLOT-1)], bm);
        }
    }
}

// Kernel 2 per step: r = (scA*Hu)/max(scA*gmaxHu,1); T = gamma*LSE2(Rn, r); track gmax(T)
__global__ __launch_bounds__(256) void combine_kernel(
        const float* __restrict__ Hu,
        const float* __restrict__ Tin,
        const float* __restrict__ gmLs,
        const float* __restrict__ gmHu,
        const float* __restrict__ gmPrev,
        float* __restrict__ Tout,
        float* __restrict__ gmT)
{
    const int tid4 = blockIdx.x*256 + threadIdx.x;   // over G*B/4
    const float scA = 1.0f / fmaxf(maxOf32(gmLs), 1.0f);
    const float scB = 1.0f / fmaxf(scA * maxOf32(gmHu), 1.0f);
    const float scP = 1.0f / fmaxf(maxOf32(gmPrev), 1.0f);

    f4 hu = ((const f4*)Hu)[tid4];
    f4 Rn = ((const f4*)Tin)[tid4] * scP;
    f4 r  = hu * (scA * scB);
    f4 t;
    float mx = 0.f;
    #pragma unroll
    for (int i = 0; i < 4; i++){
        float M = fmaxf(Rn[i], r[i]);
        float v = M + GLN2 * flog2(fexp2((Rn[i]-M)*K_E) + fexp2((r[i]-M)*K_E));
        t[i] = v;
        mx = fmaxf(mx, v);
    }
    ((f4*)Tout)[tid4] = t;
    float wm = waveMax(mx);
    if ((threadIdx.x & 63) == 0) atomicMaxF(&gmT[blockIdx.x & (NSLOT-1)], wm);
}

// final: out[b*G+g] = T[g*B+b] / max(gmaxT,1)
__global__ void output_kernel(const float* __restrict__ T, const float* __restrict__ gmT,
                              float* __restrict__ out){
    int tid = blockIdx.x*256 + threadIdx.x;   // b*G+g
    int b = tid >> 13;
    int g = tid & (G-1);
    float sc = 1.0f / fmaxf(maxOf32(gmT), 1.0f);
    out[tid] = T[g*B + b] * sc;
}

extern "C" void kernel_launch(void* const* d_in, const int* in_sizes, int n_in,
                              void* d_out, int out_size, void* d_ws, size_t ws_size,
                              hipStream_t stream) {
    const float* x = (const float*)d_in[0];
    const float* W = (const float*)d_in[1];
    const int*   I = (const int*)d_in[2];
    // d_in[3] = infer_step (device scalar); fixed at 4 by setup_inputs.

    float* ws    = (float*)d_ws;
    float* wstar = ws;                 // 16
    float* gm    = ws + 16;            // 4*96 + 32 = 416
    float* T0    = ws + 16 + 416;      // G*B   (16+416=432, 432*4B is 16B-aligned)
    float* T1    = T0 + G*B;
    float* Hu    = T1 + G*B;

    float* out = (float*)d_out;

    init_kernel<<<1, 64, 0, stream>>>(W, wstar, gm);
    transpose_kernel<<<(B*G)/256, 256, 0, stream>>>(x, T0);

    float* bufs[2] = {T0, T1};
    for (int s = 0; s < STEPS; s++){
        float* Tin  = bufs[s & 1];
        float* Tout = bufs[(s+1) & 1];
        float* gmLs = gm + s*96;
        float* gmHu = gm + s*96 + 32;
        float* gmT  = gm + s*96 + 64;
        const float* gmPrev = (s == 0) ? (gm + 4*96) : (gm + (s-1)*96 + 64);
        clause_kernel<<<G, 256, 0, stream>>>(Tin, I, wstar, gmPrev, gmLs, gmHu, Hu);
        combine_kernel<<<(G*B/4)/256, 256, 0, stream>>>(Hu, Tin, gmLs, gmHu,
                                                        gmPrev, Tout, gmT);
    }
    output_kernel<<<(B*G)/256, 256, 0, stream>>>(bufs[STEPS & 1], gm + (STEPS-1)*96 + 64, out);
}

// Round 3
// 230.733 us; speedup vs baseline: 2.4730x; 2.4730x over previous
//
#include <hip/hip_runtime.h>

// Problem constants: B=16, G=8192, C=16, S=8, L=3, m=1, infer_step=4
constexpr int B = 16;
constexpr int G = 8192;
constexpr int C = 16;
constexpr int S = 8;
constexpr int L = 3;
constexpr int STEPS = 4;
constexpr int NSLOT = 32;       // max-slots, each on its own 64B line (stride 16 floats)
constexpr int SLOT_STRIDE = 16; // floats between slots
constexpr int ARR = NSLOT * SLOT_STRIDE;  // 512 floats per slot-array

#define K_E   144.269504088896f   // 1/(gamma*ln2), gamma=0.01
#define GLN2  0.00693147180560f   // gamma*ln2

typedef float f4 __attribute__((ext_vector_type(4)));

__device__ __forceinline__ float fexp2(float x){ return __builtin_amdgcn_exp2f(x); }
__device__ __forceinline__ float flog2(float x){ return __builtin_amdgcn_logf(x); }

// all tracked values are >= 0, so uint-bit compare == float compare
__device__ __forceinline__ void atomicMaxF(float* p, float v){
    atomicMax(reinterpret_cast<unsigned int*>(p), __float_as_uint(v));
}

__device__ __forceinline__ float waveMax(float v){
    #pragma unroll
    for (int off = 32; off > 0; off >>= 1)
        v = fmaxf(v, __shfl_down(v, off));
    return v;
}

// Wave-cooperative reduction of the 32 spread slots: ONE gather instruction,
// shfl_xor tree, broadcast. Replaces the per-thread 32-load loop (R2's poison).
__device__ __forceinline__ float waveSlotMax(const float* __restrict__ slots){
    float v = slots[(threadIdx.x & 31) << 4];   // lanes 0-31 and 32-63 read same 32 lines
    v = fmaxf(v, __shfl_xor(v, 16));
    v = fmaxf(v, __shfl_xor(v, 8));
    v = fmaxf(v, __shfl_xor(v, 4));
    v = fmaxf(v, __shfl_xor(v, 2));
    v = fmaxf(v, __shfl_xor(v, 1));
    return __builtin_amdgcn_readfirstlane(v);
}

// ws float layout:
//   [0..15]                 wstar
//   [16 .. 16+13*512)       slot arrays, 512 floats each:
//       arr k = s*3 + {0: Ls, 1: Hu, 2: T} for step s; k=12: identity (max=1)
//   then T0 (G*B), T1 (G*B), Hu (G*B)

__global__ void init_kernel(const float* __restrict__ W, float* __restrict__ wstar,
                            float* __restrict__ slots){
    int t = threadIdx.x;
    for (int i = t; i < 13*ARR; i += 256) slots[i] = 0.f;
    if (t == 0){
        slots[12*ARR] = 1.0f;   // identity prev-max array: max = 1
        float mx = -1e30f;
        for (int c = 0; c < C; c++) mx = fmaxf(mx, W[c]);
        float e[C]; float s = 0.f;
        for (int c = 0; c < C; c++){ e[c] = fexp2((W[c]-mx)*1.44269504089f); s += e[c]; }
        for (int c = 0; c < C; c++) wstar[c] = e[c] / s;
    }
}

// x (B,G) -> T0 (G,B)
__global__ void transpose_kernel(const float* __restrict__ x, float* __restrict__ T0){
    int tid = blockIdx.x*256 + threadIdx.x;      // tid = b*G + g
    int b = tid >> 13;                           // G = 8192
    int g = tid & (G-1);
    T0[g*B + b] = x[tid];
}

// Kernel 1 per step: one block per g (8192 blocks), 256 threads = 16 c x 16 b.
// Thread (c,b): gather 24 state values (16-lane b-groups read full 64B rows,
// coalesced), body products, LSE over S=8 -> ls.  Block-reduce Hu over c.
__global__ __launch_bounds__(256) void clause_kernel(
        const float* __restrict__ Tin,      // (G,B) unnormalized state
        const int*   __restrict__ I,        // (C,G,S,L)
        const float* __restrict__ wstar,    // (C)
        const float* __restrict__ slotPrev, // spread slots: max -> prev T gmax
        float* __restrict__ slotLs,         // spread slots atomic out
        float* __restrict__ slotHu,         // spread slots atomic out
        float* __restrict__ Hu)             // (G,B) out
{
    const int tid = threadIdx.x;
    const int c = tid >> 4;
    const int b = tid & 15;
    const int g = blockIdx.x;

    const float scPrev = 1.0f / fmaxf(waveSlotMax(slotPrev), 1.0f);
    const float sc3 = scPrev * scPrev * scPrev;

    const int* Ip = I + ((size_t)c*G + g) * (S*L);
    int idx[S*L];
    #pragma unroll
    for (int i = 0; i < 6; i++){
        int4 v = ((const int4*)Ip)[i];
        idx[i*4+0] = v.x; idx[i*4+1] = v.y; idx[i*4+2] = v.z; idx[i*4+3] = v.w;
    }

    float gv[S*L];
    #pragma unroll
    for (int j = 0; j < S*L; j++) gv[j] = Tin[idx[j]*B + b];

    float body[S];
    #pragma unroll
    for (int s = 0; s < S; s++) body[s] = gv[s*3+0] * gv[s*3+1] * gv[s*3+2] * sc3;

    float m = body[0];
    #pragma unroll
    for (int s = 1; s < S; s++) m = fmaxf(m, body[s]);
    float sum = 0.f;
    #pragma unroll
    for (int s = 0; s < S; s++) sum += fexp2((body[s] - m) * K_E);
    const float ls = m + GLN2 * flog2(sum);

    __shared__ float wls[C*17];
    __shared__ float smax[4];
    wls[c*17 + b] = wstar[c] * ls;
    float wm = waveMax(ls);
    if ((tid & 63) == 0) smax[tid >> 6] = wm;
    __syncthreads();

    float hu = 0.f;
    if (tid < 16){
        #pragma unroll
        for (int cc = 0; cc < C; cc++) hu += wls[cc*17 + tid];
        Hu[(size_t)g*B + tid] = hu;
    }
    if (tid < 64){
        float wmh = waveMax(hu);   // lanes >=16 contribute 0
        if (tid == 0){
            atomicMaxF(&slotHu[(g & (NSLOT-1)) << 4], wmh);
            float bm = fmaxf(fmaxf(smax[0], smax[1]), fmaxf(smax[2], smax[3]));
            atomicMaxF(&slotLs[(g & (NSLOT-1)) << 4], bm);
        }
    }
}

// Kernel 2 per step: r = (scA*Hu)/max(scA*gmaxHu,1); T = gamma*LSE2(Rn, r); track gmax(T)
__global__ __launch_bounds__(256) void combine_kernel(
        const float* __restrict__ Hu,
        const float* __restrict__ Tin,
        const float* __restrict__ slotLs,
        const float* __restrict__ slotHu,
        const float* __restrict__ slotPrev,
        float* __restrict__ Tout,
        float* __restrict__ slotT)
{
    const float scA = 1.0f / fmaxf(waveSlotMax(slotLs), 1.0f);
    const float scB = 1.0f / fmaxf(scA * waveSlotMax(slotHu), 1.0f);
    const float scP = 1.0f / fmaxf(waveSlotMax(slotPrev), 1.0f);

    const int tid4 = blockIdx.x*256 + threadIdx.x;   // over G*B/4
    f4 hu = ((const f4*)Hu)[tid4];
    f4 Rn = ((const f4*)Tin)[tid4] * scP;
    f4 r  = hu * (scA * scB);
    f4 t;
    float mx = 0.f;
    #pragma unroll
    for (int i = 0; i < 4; i++){
        float M = fmaxf(Rn[i], r[i]);
        float v = M + GLN2 * flog2(fexp2((Rn[i]-M)*K_E) + fexp2((r[i]-M)*K_E));
        t[i] = v;
        mx = fmaxf(mx, v);
    }
    ((f4*)Tout)[tid4] = t;
    float wm = waveMax(mx);
    if ((threadIdx.x & 63) == 0)
        atomicMaxF(&slotT[(blockIdx.x & (NSLOT-1)) << 4], wm);
}

// final: out[b*G+g] = T[g*B+b] / max(gmaxT,1)
__global__ void output_kernel(const float* __restrict__ T, const float* __restrict__ slotT,
                              float* __restrict__ out){
    float sc = 1.0f / fmaxf(waveSlotMax(slotT), 1.0f);
    int tid = blockIdx.x*256 + threadIdx.x;   // b*G+g
    int b = tid >> 13;
    int g = tid & (G-1);
    out[tid] = T[g*B + b] * sc;
}

extern "C" void kernel_launch(void* const* d_in, const int* in_sizes, int n_in,
                              void* d_out, int out_size, void* d_ws, size_t ws_size,
                              hipStream_t stream) {
    const float* x = (const float*)d_in[0];
    const float* W = (const float*)d_in[1];
    const int*   I = (const int*)d_in[2];
    // d_in[3] = infer_step (device scalar); fixed at 4 by setup_inputs.

    float* ws    = (float*)d_ws;
    float* wstar = ws;                  // 16
    float* slots = ws + 16;             // 13*512 = 6656
    float* T0    = ws + 16 + 13*ARR;    // 6672 floats in -> 16B aligned
    float* T1    = T0 + G*B;
    float* Hu    = T1 + G*B;

    float* out = (float*)d_out;

    init_kernel<<<1, 256, 0, stream>>>(W, wstar, slots);
    transpose_kernel<<<(B*G)/256, 256, 0, stream>>>(x, T0);

    float* bufs[2] = {T0, T1};
    for (int s = 0; s < STEPS; s++){
        float* Tin  = bufs[s & 1];
        float* Tout = bufs[(s+1) & 1];
        float* slotLs = slots + (s*3 + 0)*ARR;
        float* slotHu = slots + (s*3 + 1)*ARR;
        float* slotT  = slots + (s*3 + 2)*ARR;
        const float* slotPrev = (s == 0) ? (slots + 12*ARR) : (slots + ((s-1)*3 + 2)*ARR);
        clause_kernel<<<G, 256, 0, stream>>>(Tin, I, wstar, slotPrev, slotLs, slotHu, Hu);
        combine_kernel<<<(G*B/4)/256, 256, 0, stream>>>(Hu, Tin, slotLs, slotHu,
                                                        slotPrev, Tout, slotT);
    }
    output_kernel<<<(B*G)/256, 256, 0, stream>>>(bufs[STEPS & 1],
                                                 slots + ((STEPS-1)*3 + 2)*ARR, out);
}

// Round 4
// 129.859 us; speedup vs baseline: 4.3940x; 1.7768x over previous
//
#include <hip/hip_runtime.h>

// Problem constants: B=16, G=8192, C=16, S=8, L=3, m=1, infer_step=4
constexpr int B = 16;
constexpr int G = 8192;
constexpr int C = 16;
constexpr int S = 8;
constexpr int L = 3;
constexpr int STEPS = 4;
constexpr int NSLOT = 64;        // max-slots, one per 64B line
constexpr int SLOT_STRIDE = 16;  // floats between slots
constexpr int ARR = NSLOT * SLOT_STRIDE;  // 1024 floats per slot-array

#define K_E   144.269504088896f   // 1/(gamma*ln2), gamma=0.01
#define GLN2  0.00693147180560f   // gamma*ln2

typedef float f4 __attribute__((ext_vector_type(4)));

__device__ __forceinline__ float fexp2(float x){ return __builtin_amdgcn_exp2f(x); }
__device__ __forceinline__ float flog2(float x){ return __builtin_amdgcn_logf(x); }

// all tracked values are >= 0, so uint-bit compare == float compare
__device__ __forceinline__ void atomicMaxF(float* p, float v){
    atomicMax(reinterpret_cast<unsigned int*>(p), __float_as_uint(v));
}

__device__ __forceinline__ float waveMax(float v){
    #pragma unroll
    for (int off = 32; off > 0; off >>= 1)
        v = fmaxf(v, __shfl_down(v, off));
    return v;
}

// Wave-cooperative reduce of 64 spread slots: one gather, shfl_xor tree, broadcast.
__device__ __forceinline__ float waveSlotMax(const float* __restrict__ slots){
    float v = slots[(threadIdx.x & 63) << 4];
    v = fmaxf(v, __shfl_xor(v, 32));
    v = fmaxf(v, __shfl_xor(v, 16));
    v = fmaxf(v, __shfl_xor(v, 8));
    v = fmaxf(v, __shfl_xor(v, 4));
    v = fmaxf(v, __shfl_xor(v, 2));
    v = fmaxf(v, __shfl_xor(v, 1));
    return __builtin_amdgcn_readfirstlane(v);
}

// ws float layout:
//   [0..15]            wstar
//   [16 .. 16+13*1024) slot arrays (1024 floats each):
//        arr k = s*3 + {0: Ls, 1: Hu, 2: T}; k=12: identity (max=1)
//   [then]             optional packed I (ushort, 6.3MB), then T0, T1, Hu

__global__ void init_kernel(const float* __restrict__ W, float* __restrict__ wstar,
                            float* __restrict__ slots){
    int t = threadIdx.x;
    for (int i = t; i < 13*ARR; i += 256) slots[i] = 0.f;
    if (t == 0){
        slots[12*ARR] = 1.0f;   // identity prev-max array
        float mx = -1e30f;
        for (int c = 0; c < C; c++) mx = fmaxf(mx, W[c]);
        float e[C]; float s = 0.f;
        for (int c = 0; c < C; c++){ e[c] = fexp2((W[c]-mx)*1.44269504089f); s += e[c]; }
        for (int c = 0; c < C; c++) wstar[c] = e[c] / s;
    }
}

// one-time: int32 indices -> uint16 (G=8192 < 65536)
__global__ void pack_kernel(const int* __restrict__ I, ushort* __restrict__ Ipk){
    int t = blockIdx.x*256 + threadIdx.x;   // each packs 4 ints
    int4 v = ((const int4*)I)[t];
    ushort4 o;
    o.x = (ushort)v.x; o.y = (ushort)v.y; o.z = (ushort)v.z; o.w = (ushort)v.w;
    ((ushort4*)Ipk)[t] = o;
}

// x (B,G) -> T0 (G,B)
__global__ void transpose_kernel(const float* __restrict__ x, float* __restrict__ T0){
    int tid = blockIdx.x*256 + threadIdx.x;      // tid = b*G + g
    int b = tid >> 13;                           // G = 8192
    int g = tid & (G-1);
    T0[g*B + b] = x[tid];
}

// Clause: ONE WAVE per g. lanes = 16 b x 4 c-subgroups; each lane does 4 c's
// serially (c = j*4+k). No LDS, no barrier; c-reduction via shfl_xor.
template<bool PACKED>
__global__ __launch_bounds__(256) void clause_kernel(
        const float*  __restrict__ Tin,      // (G,B) unnormalized state
        const int*    __restrict__ I32,      // (C,G,S,L) original
        const ushort* __restrict__ I16,      // packed (or null)
        const float*  __restrict__ wstar,    // (C)
        const float*  __restrict__ slotPrev,
        float* __restrict__ slotLs,
        float* __restrict__ slotHu,
        float* __restrict__ Hu)              // (G,B) out
{
    const int lane = threadIdx.x & 63;
    const int g    = blockIdx.x*4 + (threadIdx.x >> 6);
    const int j    = lane >> 4;              // c-subgroup
    const int b    = lane & 15;

    const float scPrev = 1.0f / fmaxf(waveSlotMax(slotPrev), 1.0f);
    const float sc3 = scPrev * scPrev * scPrev;

    const f4 wst4 = *(const f4*)(wstar + j*4);   // this lane's 4 clause weights

    float humix = 0.f, lsmax = 0.f;
    #pragma unroll 2
    for (int k = 0; k < 4; k++){
        const int c = j*4 + k;
        int idx[S*L];
        if (PACKED){
            const uint4* p = (const uint4*)(I16 + (size_t)(c*G + g)*(S*L));
            uint4 d0 = p[0], d1 = p[1], d2 = p[2];
            unsigned dw[12] = {d0.x,d0.y,d0.z,d0.w, d1.x,d1.y,d1.z,d1.w, d2.x,d2.y,d2.z,d2.w};
            #pragma unroll
            for (int i = 0; i < 12; i++){
                idx[2*i]   = (int)(dw[i] & 0xFFFFu);
                idx[2*i+1] = (int)(dw[i] >> 16);
            }
        } else {
            const int4* p = (const int4*)(I32 + (size_t)(c*G + g)*(S*L));
            #pragma unroll
            for (int i = 0; i < 6; i++){
                int4 v = p[i];
                idx[4*i] = v.x; idx[4*i+1] = v.y; idx[4*i+2] = v.z; idx[4*i+3] = v.w;
            }
        }
        float gv[S*L];
        #pragma unroll
        for (int t = 0; t < S*L; t++) gv[t] = Tin[idx[t]*B + b];

        float body[S];
        #pragma unroll
        for (int s = 0; s < S; s++) body[s] = gv[3*s] * gv[3*s+1] * gv[3*s+2] * sc3;

        float m = body[0];
        #pragma unroll
        for (int s = 1; s < S; s++) m = fmaxf(m, body[s]);
        float sum = 0.f;
        #pragma unroll
        for (int s = 0; s < S; s++) sum += fexp2((body[s] - m) * K_E);
        float ls = m + GLN2 * flog2(sum);

        lsmax = fmaxf(lsmax, ls);
        humix = __builtin_fmaf(wst4[k], ls, humix);
    }

    // reduce over the 4 c-subgroups (lanes differing in bits 4,5)
    humix += __shfl_xor(humix, 16);
    humix += __shfl_xor(humix, 32);

    if (lane < 16) Hu[(size_t)g*B + lane] = humix;   // one 64B line

    float wl = waveMax(lsmax);
    float wh = waveMax(humix);
    if (lane == 0){
        atomicMaxF(&slotLs[(g & (NSLOT-1)) << 4], wl);
        atomicMaxF(&slotHu[(g & (NSLOT-1)) << 4], wh);
    }
}

// Combine: r = (scA*Hu)/max(scA*gmaxHu,1); T = gamma*LSE2(Rn, r); track gmax(T)
__global__ __launch_bounds__(256) void combine_kernel(
        const float* __restrict__ Hu,
        const float* __restrict__ Tin,
        const float* __restrict__ slotLs,
        const float* __restrict__ slotHu,
        const float* __restrict__ slotPrev,
        float* __restrict__ Tout,
        float* __restrict__ slotT)
{
    const float scA = 1.0f / fmaxf(waveSlotMax(slotLs), 1.0f);
    const float scB = 1.0f / fmaxf(scA * waveSlotMax(slotHu), 1.0f);
    const float scP = 1.0f / fmaxf(waveSlotMax(slotPrev), 1.0f);

    const int t = blockIdx.x*256 + threadIdx.x;   // over G*B
    float r  = Hu[t] * (scA * scB);
    float Rn = Tin[t] * scP;
    float M  = fmaxf(Rn, r);
    float v  = M + GLN2 * flog2(fexp2((Rn-M)*K_E) + fexp2((r-M)*K_E));
    Tout[t] = v;
    float wm = waveMax(v);
    if ((threadIdx.x & 63) == 0)
        atomicMaxF(&slotT[(blockIdx.x & (NSLOT-1)) << 4], wm);
}

// final: out[b*G+g] = T[g*B+b] / max(gmaxT,1)
__global__ void output_kernel(const float* __restrict__ T, const float* __restrict__ slotT,
                              float* __restrict__ out){
    float sc = 1.0f / fmaxf(waveSlotMax(slotT), 1.0f);
    int tid = blockIdx.x*256 + threadIdx.x;   // b*G+g
    int b = tid >> 13;
    int g = tid & (G-1);
    out[tid] = T[g*B + b] * sc;
}

extern "C" void kernel_launch(void* const* d_in, const int* in_sizes, int n_in,
                              void* d_out, int out_size, void* d_ws, size_t ws_size,
                              hipStream_t stream) {
    const float* x = (const float*)d_in[0];
    const float* W = (const float*)d_in[1];
    const int*   I = (const int*)d_in[2];
    // d_in[3] = infer_step (device scalar); fixed at 4 by setup_inputs.

    const size_t baseF   = 16 + 13*ARR;          // wstar + slots
    const size_t packF   = (size_t)C*G*S*L / 2;  // packed I as float-equivalents
    const size_t stateF  = (size_t)G*B;
    const bool packed = ws_size >= (baseF + packF + 3*stateF) * sizeof(float);

    float* ws    = (float*)d_ws;
    float* wstar = ws;
    float* slots = ws + 16;
    ushort* Ipk  = (ushort*)(ws + baseF);
    float* T0    = ws + baseF + (packed ? packF : 0);
    float* T1    = T0 + stateF;
    float* Hu    = T1 + stateF;

    float* out = (float*)d_out;

    init_kernel<<<1, 256, 0, stream>>>(W, wstar, slots);
    if (packed) pack_kernel<<<(C*G*S*L/4)/256, 256, 0, stream>>>(I, Ipk);
    transpose_kernel<<<(B*G)/256, 256, 0, stream>>>(x, T0);

    float* bufs[2] = {T0, T1};
    for (int s = 0; s < STEPS; s++){
        float* Tin  = bufs[s & 1];
        float* Tout = bufs[(s+1) & 1];
        float* slotLs = slots + (s*3 + 0)*ARR;
        float* slotHu = slots + (s*3 + 1)*ARR;
        float* slotT  = slots + (s*3 + 2)*ARR;
        const float* slotPrev = (s == 0) ? (slots + 12*ARR) : (slots + ((s-1)*3 + 2)*ARR);
        if (packed)
            clause_kernel<true><<<G/4, 256, 0, stream>>>(Tin, I, Ipk, wstar, slotPrev,
                                                         slotLs, slotHu, Hu);
        else
            clause_kernel<false><<<G/4, 256, 0, stream>>>(Tin, I, Ipk, wstar, slotPrev,
                                                          slotLs, slotHu, Hu);
        combine_kernel<<<(G*B)/256, 256, 0, stream>>>(Hu, Tin, slotLs, slotHu,
                                                      slotPrev, Tout, slotT);
    }
    output_kernel<<<(B*G)/256, 256, 0, stream>>>(bufs[STEPS & 1],
                                                 slots + ((STEPS-1)*3 + 2)*ARR, out);
}

// Round 5
// 119.220 us; speedup vs baseline: 4.7861x; 1.0892x over previous
//
#include <hip/hip_runtime.h>
#include <hip/hip_fp16.h>

// Problem constants: B=16, G=8192, C=16, S=8, L=3, m=1, infer_step=4
constexpr int B = 16;
constexpr int G = 8192;
constexpr int C = 16;
constexpr int S = 8;
constexpr int L = 3;
constexpr int STEPS = 4;
constexpr int NSLOT = 64;        // max-slots, one per 64B line
constexpr int SLOT_STRIDE = 16;  // floats between slots
constexpr int ARR = NSLOT * SLOT_STRIDE;  // 1024 floats per slot-array

#define K_E   144.269504088896f   // 1/(gamma*ln2), gamma=0.01
#define GLN2  0.00693147180560f   // gamma*ln2

typedef float f4 __attribute__((ext_vector_type(4)));

__device__ __forceinline__ float fexp2(float x){ return __builtin_amdgcn_exp2f(x); }
__device__ __forceinline__ float flog2(float x){ return __builtin_amdgcn_logf(x); }

__device__ __forceinline__ void atomicMaxF(float* p, float v){
    atomicMax(reinterpret_cast<unsigned int*>(p), __float_as_uint(v));
}

__device__ __forceinline__ float waveMax(float v){
    #pragma unroll
    for (int off = 32; off > 0; off >>= 1)
        v = fmaxf(v, __shfl_down(v, off));
    return v;
}

// Wave-cooperative reduce of 64 spread slots: one gather, shfl_xor tree, broadcast.
__device__ __forceinline__ float waveSlotMax(const float* __restrict__ slots){
    float v = slots[(threadIdx.x & 63) << 4];
    v = fmaxf(v, __shfl_xor(v, 32));
    v = fmaxf(v, __shfl_xor(v, 16));
    v = fmaxf(v, __shfl_xor(v, 8));
    v = fmaxf(v, __shfl_xor(v, 4));
    v = fmaxf(v, __shfl_xor(v, 2));
    v = fmaxf(v, __shfl_xor(v, 1));
    return __builtin_amdgcn_readfirstlane(v);
}

// ---------------------------------------------------------------------------
// prep: fused pack (I -> u16), transpose (x -> T0 fp32 + fp16 shadow), init.
// Grid (packed): 3072 pack blocks + 512 transpose blocks + 1 init block.
// Grid (fallback): 512 transpose + 1 init.
template<bool PK>
__global__ __launch_bounds__(256) void prep_kernel(
        const float* __restrict__ x, const int* __restrict__ I,
        const float* __restrict__ W,
        float* __restrict__ wstar, float* __restrict__ slots,
        ushort* __restrict__ Ipk,
        float* __restrict__ T0, __half* __restrict__ T0h)
{
    constexpr int NPACK = PK ? (C*G*S*L/4)/256 : 0;   // 3072 or 0
    const int bid = blockIdx.x;
    if (PK && bid < NPACK){
        int t = bid*256 + threadIdx.x;
        int4 v = ((const int4*)I)[t];
        ushort4 o;
        o.x = (ushort)v.x; o.y = (ushort)v.y; o.z = (ushort)v.z; o.w = (ushort)v.w;
        ((ushort4*)Ipk)[t] = o;
    } else if (bid < NPACK + (B*G)/256){
        int t = (bid - NPACK)*256 + threadIdx.x;  // t = b*G + g
        int b = t >> 13;
        int g = t & (G-1);
        float v = x[t];
        T0[g*B + b] = v;
        if (PK) T0h[g*B + b] = __float2half(v);
    } else {
        int t = threadIdx.x;
        for (int i = t; i < 13*ARR; i += 256) slots[i] = 0.f;
        if (t == 0){
            slots[12*ARR] = 1.0f;   // identity prev-max array
            float mx = -1e30f;
            for (int c = 0; c < C; c++) mx = fmaxf(mx, W[c]);
            float e[C]; float s = 0.f;
            for (int c = 0; c < C; c++){ e[c] = fexp2((W[c]-mx)*1.44269504089f); s += e[c]; }
            for (int c = 0; c < C; c++) wstar[c] = e[c] / s;
        }
    }
}

// ---------------------------------------------------------------------------
// Clause (primary): ONE WAVE per g, fp16 state gathers, packed u16 indices.
// lanes = 16 b x 4 c-subgroups; each lane does 4 c's serially.
__global__ __launch_bounds__(256) void clause_h(
        const __half*  __restrict__ Tin16,   // (G,B) fp16 shadow of state
        const ushort*  __restrict__ I16,     // packed indices
        const float*   __restrict__ wstar,
        const float*   __restrict__ slotPrev,
        float* __restrict__ slotLs,
        float* __restrict__ slotHu,
        float* __restrict__ Hu)              // (G,B) fp32 out
{
    const int lane = threadIdx.x & 63;
    const int g    = blockIdx.x*4 + (threadIdx.x >> 6);
    const int j    = lane >> 4;
    const int b    = lane & 15;

    const float scPrev = 1.0f / fmaxf(waveSlotMax(slotPrev), 1.0f);
    const float sc3 = scPrev * scPrev * scPrev;

    const f4 wst4 = *(const f4*)(wstar + j*4);

    float humix = 0.f, lsmax = 0.f;
    #pragma unroll 2
    for (int k = 0; k < 4; k++){
        const int c = j*4 + k;
        const uint4* p = (const uint4*)(I16 + (size_t)(c*G + g)*(S*L));
        uint4 d0 = p[0], d1 = p[1], d2 = p[2];
        unsigned dw[12] = {d0.x,d0.y,d0.z,d0.w, d1.x,d1.y,d1.z,d1.w, d2.x,d2.y,d2.z,d2.w};
        int idx[S*L];
        #pragma unroll
        for (int i = 0; i < 12; i++){
            idx[2*i]   = (int)(dw[i] & 0xFFFFu);
            idx[2*i+1] = (int)(dw[i] >> 16);
        }
        float gv[S*L];
        #pragma unroll
        for (int t = 0; t < S*L; t++) gv[t] = __half2float(Tin16[idx[t]*B + b]);

        float body[S];
        #pragma unroll
        for (int s = 0; s < S; s++) body[s] = gv[3*s] * gv[3*s+1] * gv[3*s+2] * sc3;

        float m = body[0];
        #pragma unroll
        for (int s = 1; s < S; s++) m = fmaxf(m, body[s]);
        float sum = 0.f;
        #pragma unroll
        for (int s = 0; s < S; s++) sum += fexp2((body[s] - m) * K_E);
        float ls = m + GLN2 * flog2(sum);

        lsmax = fmaxf(lsmax, ls);
        humix = __builtin_fmaf(wst4[k], ls, humix);
    }

    humix += __shfl_xor(humix, 16);
    humix += __shfl_xor(humix, 32);

    if (lane < 16) Hu[(size_t)g*B + lane] = humix;

    float wl = waveMax(lsmax);
    float wh = waveMax(humix);
    if (lane == 0){
        atomicMaxF(&slotLs[(g & (NSLOT-1)) << 4], wl);
        atomicMaxF(&slotHu[(g & (NSLOT-1)) << 4], wh);
    }
}

// Fallback clause (fp32 state, unpacked int32 I) — R4-proven path.
__global__ __launch_bounds__(256) void clause_f(
        const float* __restrict__ Tin,
        const int*   __restrict__ I32,
        const float* __restrict__ wstar,
        const float* __restrict__ slotPrev,
        float* __restrict__ slotLs,
        float* __restrict__ slotHu,
        float* __restrict__ Hu)
{
    const int lane = threadIdx.x & 63;
    const int g    = blockIdx.x*4 + (threadIdx.x >> 6);
    const int j    = lane >> 4;
    const int b    = lane & 15;

    const float scPrev = 1.0f / fmaxf(waveSlotMax(slotPrev), 1.0f);
    const float sc3 = scPrev * scPrev * scPrev;
    const f4 wst4 = *(const f4*)(wstar + j*4);

    float humix = 0.f, lsmax = 0.f;
    #pragma unroll 2
    for (int k = 0; k < 4; k++){
        const int c = j*4 + k;
        const int4* p = (const int4*)(I32 + (size_t)(c*G + g)*(S*L));
        int idx[S*L];
        #pragma unroll
        for (int i = 0; i < 6; i++){
            int4 v = p[i];
            idx[4*i] = v.x; idx[4*i+1] = v.y; idx[4*i+2] = v.z; idx[4*i+3] = v.w;
        }
        float gv[S*L];
        #pragma unroll
        for (int t = 0; t < S*L; t++) gv[t] = Tin[idx[t]*B + b];

        float body[S];
        #pragma unroll
        for (int s = 0; s < S; s++) body[s] = gv[3*s] * gv[3*s+1] * gv[3*s+2] * sc3;

        float m = body[0];
        #pragma unroll
        for (int s = 1; s < S; s++) m = fmaxf(m, body[s]);
        float sum = 0.f;
        #pragma unroll
        for (int s = 0; s < S; s++) sum += fexp2((body[s] - m) * K_E);
        float ls = m + GLN2 * flog2(sum);

        lsmax = fmaxf(lsmax, ls);
        humix = __builtin_fmaf(wst4[k], ls, humix);
    }

    humix += __shfl_xor(humix, 16);
    humix += __shfl_xor(humix, 32);
    if (lane < 16) Hu[(size_t)g*B + lane] = humix;

    float wl = waveMax(lsmax);
    float wh = waveMax(humix);
    if (lane == 0){
        atomicMaxF(&slotLs[(g & (NSLOT-1)) << 4], wl);
        atomicMaxF(&slotHu[(g & (NSLOT-1)) << 4], wh);
    }
}

// ---------------------------------------------------------------------------
// Combine: r = (scA*Hu)/max(scA*gmaxHu,1); T = gamma*LSE2(Rn, r); track gmax(T).
// Writes fp32 state + (PK) fp16 shadow for the next clause's gathers.
template<bool PK>
__global__ __launch_bounds__(256) void combine_kernel(
        const float* __restrict__ Hu,
        const float* __restrict__ Tin,
        const float* __restrict__ slotLs,
        const float* __restrict__ slotHu,
        const float* __restrict__ slotPrev,
        float* __restrict__ Tout,
        __half* __restrict__ Tout16,
        float* __restrict__ slotT)
{
    const float scA = 1.0f / fmaxf(waveSlotMax(slotLs), 1.0f);
    const float scB = 1.0f / fmaxf(scA * waveSlotMax(slotHu), 1.0f);
    const float scP = 1.0f / fmaxf(waveSlotMax(slotPrev), 1.0f);

    const int t = blockIdx.x*256 + threadIdx.x;   // over G*B
    float r  = Hu[t] * (scA * scB);
    float Rn = Tin[t] * scP;
    float M  = fmaxf(Rn, r);
    float v  = M + GLN2 * flog2(fexp2((Rn-M)*K_E) + fexp2((r-M)*K_E));
    Tout[t] = v;
    if (PK) Tout16[t] = __float2half(v);
    float wm = waveMax(v);
    if ((threadIdx.x & 63) == 0)
        atomicMaxF(&slotT[(blockIdx.x & (NSLOT-1)) << 4], wm);
}

// final: out[b*G+g] = T[g*B+b] / max(gmaxT,1)
__global__ void output_kernel(const float* __restrict__ T, const float* __restrict__ slotT,
                              float* __restrict__ out){
    float sc = 1.0f / fmaxf(waveSlotMax(slotT), 1.0f);
    int tid = blockIdx.x*256 + threadIdx.x;   // b*G+g
    int b = tid >> 13;
    int g = tid & (G-1);
    out[tid] = T[g*B + b] * sc;
}

extern "C" void kernel_launch(void* const* d_in, const int* in_sizes, int n_in,
                              void* d_out, int out_size, void* d_ws, size_t ws_size,
                              hipStream_t stream) {
    const float* x = (const float*)d_in[0];
    const float* W = (const float*)d_in[1];
    const int*   I = (const int*)d_in[2];
    // d_in[3] = infer_step (device scalar); fixed at 4 by setup_inputs.

    const size_t baseF  = 16 + 13*ARR;           // wstar + slots
    const size_t packF  = (size_t)C*G*S*L / 2;   // packed I, in float units
    const size_t stateF = (size_t)G*B;
    const size_t halfF  = (size_t)G*B / 2;       // fp16 shadow, in float units
    const bool packed = ws_size >= (baseF + packF + 3*stateF + 2*halfF) * sizeof(float);

    float* ws    = (float*)d_ws;
    float* wstar = ws;
    float* slots = ws + 16;
    ushort* Ipk  = (ushort*)(ws + baseF);
    float* T0    = ws + baseF + (packed ? packF : 0);
    float* T1    = T0 + stateF;
    float* Hu    = T1 + stateF;
    __half* T0h  = (__half*)(Hu + stateF);
    __half* T1h  = T0h + G*B;

    float* out = (float*)d_out;

    if (packed){
        prep_kernel<true><<<(C*G*S*L/4)/256 + (B*G)/256 + 1, 256, 0, stream>>>(
            x, I, W, wstar, slots, Ipk, T0, T0h);
    } else {
        prep_kernel<false><<<(B*G)/256 + 1, 256, 0, stream>>>(
            x, I, W, wstar, slots, Ipk, T0, T0h);
    }

    float* bufs[2]  = {T0, T1};
    __half* bufsh[2] = {T0h, T1h};
    for (int s = 0; s < STEPS; s++){
        float*  Tin   = bufs[s & 1];
        float*  Tout  = bufs[(s+1) & 1];
        __half* Tinh  = bufsh[s & 1];
        __half* Touth = bufsh[(s+1) & 1];
        float* slotLs = slots + (s*3 + 0)*ARR;
        float* slotHu = slots + (s*3 + 1)*ARR;
        float* slotT  = slots + (s*3 + 2)*ARR;
        const float* slotPrev = (s == 0) ? (slots + 12*ARR) : (slots + ((s-1)*3 + 2)*ARR);
        if (packed){
            clause_h<<<G/4, 256, 0, stream>>>(Tinh, Ipk, wstar, slotPrev,
                                              slotLs, slotHu, Hu);
            combine_kernel<true><<<(G*B)/256, 256, 0, stream>>>(Hu, Tin, slotLs, slotHu,
                                                                slotPrev, Tout, Touth, slotT);
        } else {
            clause_f<<<G/4, 256, 0, stream>>>(Tin, I, wstar, slotPrev,
                                              slotLs, slotHu, Hu);
            combine_kernel<false><<<(G*B)/256, 256, 0, stream>>>(Hu, Tin, slotLs, slotHu,
                                                                 slotPrev, Tout, Touth, slotT);
        }
    }
    output_kernel<<<(B*G)/256, 256, 0, stream>>>(bufs[STEPS & 1],
                                                 slots + ((STEPS-1)*3 + 2)*ARR, out);
}